// Round 9
// baseline (564.560 us; speedup 1.0000x reference)
//
#include <hip/hip_runtime.h>
#include <hip/hip_bf16.h>

#define HID 128

typedef __attribute__((ext_vector_type(8))) short short8;
typedef __attribute__((ext_vector_type(4))) float f32x4;

__device__ __forceinline__ unsigned short f2bf(float f) {
    unsigned int u = __builtin_bit_cast(unsigned int, f);
    u += 0x7FFFu + ((u >> 16) & 1u);            // round-to-nearest-even
    return (unsigned short)(u >> 16);
}
__device__ __forceinline__ float bf2f(unsigned short h) {
    unsigned int u = ((unsigned int)h) << 16;
    return __builtin_bit_cast(float, u);
}

// ---------------- prep: x -> bf16 ----------------
__global__ void prep_x(const float4* __restrict__ x4, unsigned short* __restrict__ xb, int n4) {
    int t = blockIdx.x * 256 + threadIdx.x;
    if (t >= n4) return;
    float4 v = x4[t];
    union { unsigned short u[4]; uint2 d; } p;
    p.u[0] = f2bf(v.x); p.u[1] = f2bf(v.y); p.u[2] = f2bf(v.z); p.u[3] = f2bf(v.w);
    *(uint2*)(xb + (size_t)t * 4) = p.d;
}

// ---------------- prep: W[k][128] -> fragment order Wf[ks][nt][lane][j] ----------------
__global__ void prep_w(const float* __restrict__ W, unsigned short* __restrict__ Wf, int nks) {
    int t = blockIdx.x * 256 + threadIdx.x;
    if (t >= nks * 8 * 64) return;
    int lane = t & 63, nt = (t >> 6) & 7, ks = t >> 9;
    int kb  = ks * 32 + ((lane >> 4) << 3);
    int col = (nt << 4) + (lane & 15);
    union { unsigned short u[8]; uint4 q; } p;
    #pragma unroll
    for (int j = 0; j < 8; ++j) p.u[j] = f2bf(W[(size_t)(kb + j) * 128 + col]);
    *(uint4*)(Wf + (size_t)t * 8) = p.q;
}

// hi/lo split version for near-fp32 node GEMMs
__global__ void prep_w_split(const float* __restrict__ W,
                             unsigned short* __restrict__ Wh,
                             unsigned short* __restrict__ Wl, int nks) {
    int t = blockIdx.x * 256 + threadIdx.x;
    if (t >= nks * 8 * 64) return;
    int lane = t & 63, nt = (t >> 6) & 7, ks = t >> 9;
    int kb  = ks * 32 + ((lane >> 4) << 3);
    int col = (nt << 4) + (lane & 15);
    union { unsigned short u[8]; uint4 q; } ph, pl;
    #pragma unroll
    for (int j = 0; j < 8; ++j) {
        float w = W[(size_t)(kb + j) * 128 + col];
        unsigned short h = f2bf(w);
        ph.u[j] = h;
        pl.u[j] = f2bf(w - bf2f(h));
    }
    *(uint4*)(Wh + (size_t)t * 8) = ph.q;
    *(uint4*)(Wl + (size_t)t * 8) = pl.q;
}

// ---------------- counting sort of edges by dst (materialized, r6-proven) ----------------
__global__ void hist_k(const int* __restrict__ ei, unsigned* __restrict__ cnt, int E) {
    int e = blockIdx.x * 256 + threadIdx.x;
    if (e < E) atomicAdd(&cnt[ei[E + e]], 1u);
}

__global__ void scan_k(const unsigned* __restrict__ cnt, unsigned* __restrict__ cur, int n) {
    __shared__ unsigned wsum[16];
    int tid = threadIdx.x, lane = tid & 63, w = tid >> 6;
    unsigned carry = 0;
    for (int base = 0; base < n; base += 1024) {
        int i = base + tid;
        unsigned v = (i < n) ? cnt[i] : 0u;
        unsigned s = v;
        #pragma unroll
        for (int off = 1; off < 64; off <<= 1) {
            unsigned t = __shfl_up(s, off);
            if (lane >= off) s += t;
        }
        if (lane == 63) wsum[w] = s;
        __syncthreads();
        if (tid < 16) {
            unsigned t = wsum[tid];
            #pragma unroll
            for (int off = 1; off < 16; off <<= 1) {
                unsigned u = __shfl_up(t, off);
                if (tid >= off) t += u;
            }
            wsum[tid] = t;
        }
        __syncthreads();
        unsigned woff = (w == 0) ? 0u : wsum[w - 1];
        if (i < n) cur[i] = carry + woff + s - v;
        unsigned tot = wsum[15];
        __syncthreads();
        carry += tot;
    }
}

__global__ void scatter_k(const int* __restrict__ ei, const float* __restrict__ ea,
                          unsigned* __restrict__ cur,
                          int* __restrict__ srcS, int* __restrict__ dstS,
                          float* __restrict__ eaS, int E) {
    int e = blockIdx.x * 256 + threadIdx.x;
    if (e >= E) return;
    int d = ei[E + e];
    unsigned pos = atomicAdd(&cur[d], 1u);
    srcS[pos] = ei[e];
    dstS[pos] = d;
    eaS[(size_t)pos * 3 + 0] = ea[(size_t)e * 3 + 0];
    eaS[(size_t)pos * 3 + 1] = ea[(size_t)e * 3 + 1];
    eaS[(size_t)pos * 3 + 2] = ea[(size_t)e * 3 + 2];
}

// ---------------- Edge kernel: persistent-B, block loops over 32-edge tiles ----------------
// 4 waves/block; wave w owns N-tiles {2w, 2w+1}; all W1/W2 B-frags live in registers.
__global__
void edge_mfma_p(const unsigned short* __restrict__ xb,   // [N][128] bf16
                 const int* __restrict__ srcS,            // [E] (dst-sorted)
                 const int* __restrict__ dstS,            // [E]
                 const float* __restrict__ eaS,           // [E][3]
                 const unsigned short* __restrict__ W1f,  // [8][8][64][8] bf16
                 const unsigned short* __restrict__ W2f,  // [4][8][64][8] bf16
                 const float* __restrict__ W1tail,        // [3][128] fp32
                 const float* __restrict__ bm1,
                 const float* __restrict__ bm2,
                 float* __restrict__ agg,
                 int E, int tiles_per_block)
{
    __shared__ alignas(16) char A[32 * 512];   // 16 KB: 32 edges x (src 256 B | dst 256 B), swizzled
    __shared__ alignas(16) char H[32 * 256];   // 8 KB
    __shared__ int   sSrc[32], sDst[32];
    __shared__ float sEA[96];

    const int tid  = threadIdx.x;
    const int lane = tid & 63;
    const int w    = tid >> 6;
    const int arow = lane & 15;
    const int kgrp = (lane >> 4) << 4;
    const int rbase = (lane >> 4) * 4;

    // ---- persistent B fragments (registers, whole kernel) ----
    short8 B1[2][8], B2[2][4];
    #pragma unroll
    for (int i = 0; i < 2; ++i) {
        int nt = w * 2 + i;
        #pragma unroll
        for (int ks = 0; ks < 8; ++ks)
            B1[i][ks] = *(const short8*)(W1f + (size_t)((ks * 8 + nt) * 64 + lane) * 8);
        #pragma unroll
        for (int ks = 0; ks < 4; ++ks)
            B2[i][ks] = *(const short8*)(W2f + (size_t)((ks * 8 + nt) * 64 + lane) * 8);
    }
    // epilogue constants for this lane's 2 columns
    float w1t[2][3], b1c[2], b2c[2];
    #pragma unroll
    for (int i = 0; i < 2; ++i) {
        int col = (w * 2 + i) * 16 + arow;
        w1t[i][0] = W1tail[col];
        w1t[i][1] = W1tail[128 + col];
        w1t[i][2] = W1tail[256 + col];
        b1c[i] = bm1[col];
        b2c[i] = bm2[col];
    }

    const int ntiles = (E + 31) / 32;
    int t0 = blockIdx.x * tiles_per_block;
    int t1 = min(t0 + tiles_per_block, ntiles);

    for (int t = t0; t < t1; ++t) {
        const int e0 = t * 32;

        // ---- phase 1: stage indices + edge attrs ----
        if (tid < 32) {
            int e = e0 + tid; int ec = (e < E) ? e : (E - 1);
            sSrc[tid] = srcS[ec];
            sDst[tid] = dstS[ec];
        } else if (tid >= 64 && tid < 160) {
            int j = tid - 64;
            int eidx = e0 + j / 3, c = j - (j / 3) * 3;
            sEA[j] = (eidx < E) ? eaS[(size_t)eidx * 3 + c] : 0.f;
        }
        __syncthreads();   // BAR1: indices ready; prev-iter GEMM1 A-reads done (they precede BAR2(t-1))

        // ---- phase 2: stage A (64 rows x 256 B; 1024 16B-chunks over 256 threads) ----
        #pragma unroll
        for (int k = 0; k < 4; ++k) {
            int g  = k * 256 + tid;
            int rr = g >> 4, c = g & 15;
            int el = rr & 31, half = rr >> 5;
            int node = half ? sDst[el] : sSrc[el];
            uint4 v = *(const uint4*)(xb + (size_t)node * 128 + c * 8);
            *(uint4*)(A + el * 512 + ((half * 256 + c * 16) ^ ((el & 15) << 4))) = v;
        }
        __syncthreads();   // BAR2: A ready

        // ---- phase 3: GEMM1 [32,256]@[256,32cols], 2 streams x 2 nt ----
        f32x4 ac1[2][2];   // [nt][stream]
        #pragma unroll
        for (int i = 0; i < 2; ++i) { ac1[i][0] = (f32x4)0.f; ac1[i][1] = (f32x4)0.f; }
        #pragma unroll
        for (int ks = 0; ks < 8; ++ks) {
            int cb = (ks * 64 + kgrp) ^ (arow << 4);
            short8 a0 = *(const short8*)(A + arow * 512        + cb);
            short8 a1 = *(const short8*)(A + (16 + arow) * 512 + cb);
            #pragma unroll
            for (int i = 0; i < 2; ++i) {
                ac1[i][0] = __builtin_amdgcn_mfma_f32_16x16x32_bf16(a0, B1[i][ks], ac1[i][0], 0, 0, 0);
                ac1[i][1] = __builtin_amdgcn_mfma_f32_16x16x32_bf16(a1, B1[i][ks], ac1[i][1], 0, 0, 0);
            }
        }

        // epilogue 1: + edge_attr (fp32 exact) + bias, relu, H -> LDS; cache dv to regs
        int dv[2][4];
        float ea0[2][4], ea1[2][4], ea2[2][4];
        #pragma unroll
        for (int m = 0; m < 2; ++m)
            #pragma unroll
            for (int r = 0; r < 4; ++r) {
                int el = m * 16 + rbase + r;
                dv[m][r]  = sDst[el];
                ea0[m][r] = sEA[el * 3 + 0];
                ea1[m][r] = sEA[el * 3 + 1];
                ea2[m][r] = sEA[el * 3 + 2];
            }
        #pragma unroll
        for (int i = 0; i < 2; ++i) {
            int col = (w * 2 + i) * 16 + arow;
            #pragma unroll
            for (int m = 0; m < 2; ++m) {
                #pragma unroll
                for (int r = 0; r < 4; ++r) {
                    int el = m * 16 + rbase + r;
                    float h = ac1[i][m][r] + b1c[i];
                    h = fmaf(ea0[m][r], w1t[i][0], h);
                    h = fmaf(ea1[m][r], w1t[i][1], h);
                    h = fmaf(ea2[m][r], w1t[i][2], h);
                    h = fmaxf(h, 0.f);
                    *(unsigned short*)(H + el * 256 + ((col * 2) ^ ((el & 15) << 4))) = f2bf(h);
                }
            }
        }
        __syncthreads();   // BAR3: H ready

        // ---- phase 4: GEMM2 [32,128]@[128,32cols] ----
        f32x4 ac2[2][2];
        #pragma unroll
        for (int i = 0; i < 2; ++i) { ac2[i][0] = (f32x4)0.f; ac2[i][1] = (f32x4)0.f; }
        #pragma unroll
        for (int ks = 0; ks < 4; ++ks) {
            int cb = (ks * 64 + kgrp) ^ (arow << 4);
            short8 a0 = *(const short8*)(H + arow * 256        + cb);
            short8 a1 = *(const short8*)(H + (16 + arow) * 256 + cb);
            #pragma unroll
            for (int i = 0; i < 2; ++i) {
                ac2[i][0] = __builtin_amdgcn_mfma_f32_16x16x32_bf16(a0, B2[i][ks], ac2[i][0], 0, 0, 0);
                ac2[i][1] = __builtin_amdgcn_mfma_f32_16x16x32_bf16(a1, B2[i][ks], ac2[i][1], 0, 0, 0);
            }
        }

        // epilogue 2: + bias, run-merged atomics (uses dv regs only)
        #pragma unroll
        for (int i = 0; i < 2; ++i) {
            int col = (w * 2 + i) * 16 + arow;
            #pragma unroll
            for (int m = 0; m < 2; ++m) {
                float carry = 0.f;
                int   cd    = -1;
                #pragma unroll
                for (int r = 0; r < 4; ++r) {
                    int eg = e0 + m * 16 + rbase + r;
                    if (eg < E) {
                        float v = ac2[i][m][r] + b2c[i];
                        if (dv[m][r] == cd) {
                            carry += v;
                        } else {
                            if (cd >= 0) unsafeAtomicAdd(agg + (size_t)cd * 128 + col, carry);
                            cd = dv[m][r];
                            carry = v;
                        }
                    }
                }
                if (cd >= 0) unsafeAtomicAdd(agg + (size_t)cd * 128 + col, carry);
            }
        }
    }
}

// ---------------- Node kernel: bf16 MFMA with hi/lo split (near-fp32) ----------------
__global__ __launch_bounds__(256, 3)
void node_mfma(const float* __restrict__ x,
               const float* __restrict__ agg,
               const unsigned short* __restrict__ WgH, const unsigned short* __restrict__ WgL,
               const unsigned short* __restrict__ Wu1H, const unsigned short* __restrict__ Wu1L,
               const unsigned short* __restrict__ Wu2H, const unsigned short* __restrict__ Wu2L,
               const float* __restrict__ bg, const float* __restrict__ bu1,
               const float* __restrict__ bu2,
               const float* __restrict__ gamma, const float* __restrict__ beta,
               float* __restrict__ out, int N)
{
    __shared__ alignas(16) char Hs[4][8192];

    const int tid  = threadIdx.x;
    const int lane = tid & 63;
    const int wid  = tid >> 6;
    const int n0   = (blockIdx.x * 4 + wid) * 16;
    if (n0 >= N) return;

    const int arow = lane & 15;
    const int g4   = lane >> 4;

    int nr = n0 + arow; if (nr >= N) nr = N - 1;
    const float* px = x   + (size_t)nr * 128 + g4 * 8;
    const float* pa = agg + (size_t)nr * 128 + g4 * 8;

    short8 ah[8], al[8];
    #pragma unroll
    for (int ks = 0; ks < 8; ++ks) {
        const float* p = (ks < 4) ? (px + ks * 32) : (pa + (ks - 4) * 32);
        float4 v0 = *(const float4*)p;
        float4 v1 = *(const float4*)(p + 4);
        float v[8] = { v0.x, v0.y, v0.z, v0.w, v1.x, v1.y, v1.z, v1.w };
        #pragma unroll
        for (int j = 0; j < 8; ++j) {
            unsigned short h = f2bf(v[j]);
            ah[ks][j] = (short)h;
            al[ks][j] = (short)f2bf(v[j] - bf2f(h));
        }
    }

    f32x4 ga[8];
    #pragma unroll
    for (int i = 0; i < 8; ++i) ga[i] = (f32x4)0.f;
    #pragma unroll
    for (int ks = 0; ks < 8; ++ks) {
        #pragma unroll
        for (int nt = 0; nt < 8; ++nt) {
            size_t o = (size_t)((ks * 8 + nt) * 64 + lane) * 8;
            short8 bh = *(const short8*)(WgH + o);
            short8 bl = *(const short8*)(WgL + o);
            ga[nt] = __builtin_amdgcn_mfma_f32_16x16x32_bf16(ah[ks], bh, ga[nt], 0, 0, 0);
            ga[nt] = __builtin_amdgcn_mfma_f32_16x16x32_bf16(al[ks], bh, ga[nt], 0, 0, 0);
            ga[nt] = __builtin_amdgcn_mfma_f32_16x16x32_bf16(ah[ks], bl, ga[nt], 0, 0, 0);
        }
    }

    f32x4 ua[8];
    #pragma unroll
    for (int i = 0; i < 8; ++i) ua[i] = (f32x4)0.f;
    #pragma unroll
    for (int ks = 0; ks < 8; ++ks) {
        #pragma unroll
        for (int nt = 0; nt < 8; ++nt) {
            size_t o = (size_t)((ks * 8 + nt) * 64 + lane) * 8;
            short8 bh = *(const short8*)(Wu1H + o);
            short8 bl = *(const short8*)(Wu1L + o);
            ua[nt] = __builtin_amdgcn_mfma_f32_16x16x32_bf16(ah[ks], bh, ua[nt], 0, 0, 0);
            ua[nt] = __builtin_amdgcn_mfma_f32_16x16x32_bf16(al[ks], bh, ua[nt], 0, 0, 0);
            ua[nt] = __builtin_amdgcn_mfma_f32_16x16x32_bf16(ah[ks], bl, ua[nt], 0, 0, 0);
        }
    }

    #pragma unroll
    for (int nt = 0; nt < 8; ++nt) {
        int col = nt * 16 + arow;
        float b1 = bu1[col];
        #pragma unroll
        for (int r = 0; r < 4; ++r) {
            int row = g4 * 4 + r;
            float u = fmaxf(ua[nt][r] + b1, 0.f);
            unsigned short h = f2bf(u);
            unsigned short l = f2bf(u - bf2f(h));
            unsigned int pk = (unsigned int)h | ((unsigned int)l << 16);
            *(unsigned int*)(&Hs[wid][row * 512 + ((col * 4) ^ ((row & 15) << 4))]) = pk;
        }
    }

    #pragma unroll
    for (int nt = 0; nt < 8; ++nt) {
        int col = nt * 16 + arow;
        float b = bg[col];
        #pragma unroll
        for (int r = 0; r < 4; ++r)
            ga[nt][r] = 1.f / (1.f + expf(-(ga[nt][r] + b)));
    }
    __syncthreads();

    f32x4 u2[8];
    #pragma unroll
    for (int i = 0; i < 8; ++i) u2[i] = (f32x4)0.f;
    #pragma unroll
    for (int ks = 0; ks < 4; ++ks) {
        int b0 = ks * 128 + g4 * 32;
        unsigned int q0[4], q1[4];
        *(uint4*)q0 = *(const uint4*)(&Hs[wid][arow * 512 + ( b0       ^ (arow << 4))]);
        *(uint4*)q1 = *(const uint4*)(&Hs[wid][arow * 512 + ((b0 + 16) ^ (arow << 4))]);
        short8 a2h, a2l;
        #pragma unroll
        for (int j = 0; j < 4; ++j) {
            a2h[j]     = (short)(q0[j] & 0xffff);
            a2l[j]     = (short)(q0[j] >> 16);
            a2h[4 + j] = (short)(q1[j] & 0xffff);
            a2l[4 + j] = (short)(q1[j] >> 16);
        }
        #pragma unroll
        for (int nt = 0; nt < 8; ++nt) {
            size_t o = (size_t)((ks * 8 + nt) * 64 + lane) * 8;
            short8 bh = *(const short8*)(Wu2H + o);
            short8 bl = *(const short8*)(Wu2L + o);
            u2[nt] = __builtin_amdgcn_mfma_f32_16x16x32_bf16(a2h, bh, u2[nt], 0, 0, 0);
            u2[nt] = __builtin_amdgcn_mfma_f32_16x16x32_bf16(a2l, bh, u2[nt], 0, 0, 0);
            u2[nt] = __builtin_amdgcn_mfma_f32_16x16x32_bf16(a2h, bl, u2[nt], 0, 0, 0);
        }
    }

    float s[4]  = {0.f, 0.f, 0.f, 0.f};
    float ss[4] = {0.f, 0.f, 0.f, 0.f};
    #pragma unroll
    for (int nt = 0; nt < 8; ++nt) {
        int col = nt * 16 + arow;
        float b2 = bu2[col];
        #pragma unroll
        for (int r = 0; r < 4; ++r) {
            int node = n0 + g4 * 4 + r;
            float xv = x[(size_t)node * 128 + col];
            float g  = ga[nt][r];
            float o  = g * (u2[nt][r] + b2) + (1.f - g) * xv;
            u2[nt][r] = o;
            s[r]  += o;
            ss[r] += o * o;
        }
    }
    #pragma unroll
    for (int off = 8; off >= 1; off >>= 1) {
        #pragma unroll
        for (int r = 0; r < 4; ++r) {
            s[r]  += __shfl_xor(s[r],  off);
            ss[r] += __shfl_xor(ss[r], off);
        }
    }
    float mu[4], rstd[4];
    #pragma unroll
    for (int r = 0; r < 4; ++r) {
        mu[r] = s[r] * (1.f / 128.f);
        float var = ss[r] * (1.f / 128.f) - mu[r] * mu[r];
        rstd[r] = rsqrtf(var + 1e-5f);
    }
    #pragma unroll
    for (int nt = 0; nt < 8; ++nt) {
        int col = nt * 16 + arow;
        float gm = gamma[col], bt = beta[col];
        #pragma unroll
        for (int r = 0; r < 4; ++r) {
            int node = n0 + g4 * 4 + r;
            if (node < N)
                out[(size_t)node * 128 + col] = (u2[nt][r] - mu[r]) * rstd[r] * gm + bt;
        }
    }
}

extern "C" void kernel_launch(void* const* d_in, const int* in_sizes, int n_in,
                              void* d_out, int out_size, void* d_ws, size_t ws_size,
                              hipStream_t stream)
{
    const float* x    = (const float*)d_in[0];
    const int*   ei   = (const int*)  d_in[1];
    const float* ea   = (const float*)d_in[2];
    const float* Wm1  = (const float*)d_in[3];
    const float* bm1  = (const float*)d_in[4];
    const float* Wm2  = (const float*)d_in[5];
    const float* bm2  = (const float*)d_in[6];
    const float* Wg   = (const float*)d_in[7];
    const float* bg   = (const float*)d_in[8];
    const float* Wu1  = (const float*)d_in[9];
    const float* bu1  = (const float*)d_in[10];
    const float* Wu2  = (const float*)d_in[11];
    const float* bu2  = (const float*)d_in[12];
    const float* gmma = (const float*)d_in[13];
    const float* beta = (const float*)d_in[14];
    float* out = (float*)d_out;

    const int N = in_sizes[0] / HID;
    const int E = in_sizes[1] / 2;

    // workspace carve-up (r6 layout)
    float*          agg  = (float*)d_ws;                             // N*128 f32
    unsigned short* xb   = (unsigned short*)(agg + (size_t)N * HID); // N*128 bf16
    unsigned short* W1f  = xb + (size_t)N * HID;                     // 32768
    unsigned short* W2f  = W1f + 32768;                              // 16384
    unsigned short* WgH  = W2f + 16384;
    unsigned short* WgL  = WgH + 32768;
    unsigned short* Wu1H = WgL + 32768;
    unsigned short* Wu1L = Wu1H + 32768;
    unsigned short* Wu2H = Wu1L + 32768;
    unsigned short* Wu2L = Wu2H + 16384;
    unsigned* cnt  = (unsigned*)(Wu2L + 16384);   // N counters
    unsigned* cur  = cnt + N;                     // N cursors
    int*      srcS = (int*)(cur + N);             // E
    int*      dstS = srcS + E;                    // E
    float*    eaS  = (float*)(dstS + E);          // E*3
    size_t need = (size_t)((char*)(eaS + (size_t)E * 3) - (char*)d_ws);
    const bool do_sort = (ws_size >= need);

    hipMemsetAsync(agg, 0, (size_t)N * HID * sizeof(float), stream);

    int n4 = N * HID / 4;
    prep_x<<<dim3((n4 + 255) / 256), dim3(256), 0, stream>>>((const float4*)x, xb, n4);
    prep_w<<<dim3(16), dim3(256), 0, stream>>>(Wm1, W1f, 8);
    prep_w<<<dim3(8),  dim3(256), 0, stream>>>(Wm2, W2f, 4);
    prep_w_split<<<dim3(16), dim3(256), 0, stream>>>(Wg,  WgH,  WgL,  8);
    prep_w_split<<<dim3(16), dim3(256), 0, stream>>>(Wu1, Wu1H, Wu1L, 8);
    prep_w_split<<<dim3(8),  dim3(256), 0, stream>>>(Wu2, Wu2H, Wu2L, 4);

    const int*   srcA = ei;
    const int*   dstA = ei + E;
    const float* eaA  = ea;
    if (do_sort) {
        hipMemsetAsync(cnt, 0, (size_t)N * sizeof(unsigned), stream);
        hist_k<<<dim3((E + 255) / 256), dim3(256), 0, stream>>>(ei, cnt, E);
        scan_k<<<dim3(1), dim3(1024), 0, stream>>>(cnt, cur, N);
        scatter_k<<<dim3((E + 255) / 256), dim3(256), 0, stream>>>(ei, ea, cur, srcS, dstS, eaS, E);
        srcA = srcS; dstA = dstS; eaA = eaS;
    }

    const int ntiles = (E + 31) / 32;
    int nblocks = 1024;
    if (nblocks > ntiles) nblocks = ntiles;
    int tpb = (ntiles + nblocks - 1) / nblocks;
    edge_mfma_p<<<dim3(nblocks), dim3(256), 0, stream>>>(
        xb, srcA, dstA, eaA, W1f, W2f, Wm1 + 256 * HID, bm1, bm2, agg, E, tpb);

    int ntilesN = (N + 15) / 16;
    node_mfma<<<dim3((ntilesN + 3) / 4), dim3(256), 0, stream>>>(
        x, agg, WgH, WgL, Wu1H, Wu1L, Wu2H, Wu2L,
        bg, bu1, bu2, gmma, beta, out, N);
}

// Round 10
// 470.524 us; speedup vs baseline: 1.1999x; 1.1999x over previous
//
#include <hip/hip_runtime.h>
#include <hip/hip_bf16.h>

#define HID 128

typedef __attribute__((ext_vector_type(8))) short short8;
typedef __attribute__((ext_vector_type(4))) float f32x4;

__device__ __forceinline__ unsigned short f2bf(float f) {
    unsigned int u = __builtin_bit_cast(unsigned int, f);
    u += 0x7FFFu + ((u >> 16) & 1u);            // round-to-nearest-even
    return (unsigned short)(u >> 16);
}
__device__ __forceinline__ float bf2f(unsigned short h) {
    unsigned int u = ((unsigned int)h) << 16;
    return __builtin_bit_cast(float, u);
}

// ---------------- prep: x -> bf16 ----------------
__global__ void prep_x(const float4* __restrict__ x4, unsigned short* __restrict__ xb, int n4) {
    int t = blockIdx.x * 256 + threadIdx.x;
    if (t >= n4) return;
    float4 v = x4[t];
    union { unsigned short u[4]; uint2 d; } p;
    p.u[0] = f2bf(v.x); p.u[1] = f2bf(v.y); p.u[2] = f2bf(v.z); p.u[3] = f2bf(v.w);
    *(uint2*)(xb + (size_t)t * 4) = p.d;
}

// ---------------- prep: W[k][128] -> fragment order Wf[ks][nt][lane][j] ----------------
__global__ void prep_w(const float* __restrict__ W, unsigned short* __restrict__ Wf, int nks) {
    int t = blockIdx.x * 256 + threadIdx.x;
    if (t >= nks * 8 * 64) return;
    int lane = t & 63, nt = (t >> 6) & 7, ks = t >> 9;
    int kb  = ks * 32 + ((lane >> 4) << 3);
    int col = (nt << 4) + (lane & 15);
    union { unsigned short u[8]; uint4 q; } p;
    #pragma unroll
    for (int j = 0; j < 8; ++j) p.u[j] = f2bf(W[(size_t)(kb + j) * 128 + col]);
    *(uint4*)(Wf + (size_t)t * 8) = p.q;
}

// hi/lo split version for near-fp32 node GEMMs
__global__ void prep_w_split(const float* __restrict__ W,
                             unsigned short* __restrict__ Wh,
                             unsigned short* __restrict__ Wl, int nks) {
    int t = blockIdx.x * 256 + threadIdx.x;
    if (t >= nks * 8 * 64) return;
    int lane = t & 63, nt = (t >> 6) & 7, ks = t >> 9;
    int kb  = ks * 32 + ((lane >> 4) << 3);
    int col = (nt << 4) + (lane & 15);
    union { unsigned short u[8]; uint4 q; } ph, pl;
    #pragma unroll
    for (int j = 0; j < 8; ++j) {
        float w = W[(size_t)(kb + j) * 128 + col];
        unsigned short h = f2bf(w);
        ph.u[j] = h;
        pl.u[j] = f2bf(w - bf2f(h));
    }
    *(uint4*)(Wh + (size_t)t * 8) = ph.q;
    *(uint4*)(Wl + (size_t)t * 8) = pl.q;
}

// ---------------- counting sort of edges by dst (materialized, r6-proven) ----------------
__global__ void hist_k(const int* __restrict__ ei, unsigned* __restrict__ cnt, int E) {
    int e = blockIdx.x * 256 + threadIdx.x;
    if (e < E) atomicAdd(&cnt[ei[E + e]], 1u);
}

__global__ void scan_k(const unsigned* __restrict__ cnt, unsigned* __restrict__ cur, int n) {
    __shared__ unsigned wsum[16];
    int tid = threadIdx.x, lane = tid & 63, w = tid >> 6;
    unsigned carry = 0;
    for (int base = 0; base < n; base += 1024) {
        int i = base + tid;
        unsigned v = (i < n) ? cnt[i] : 0u;
        unsigned s = v;
        #pragma unroll
        for (int off = 1; off < 64; off <<= 1) {
            unsigned t = __shfl_up(s, off);
            if (lane >= off) s += t;
        }
        if (lane == 63) wsum[w] = s;
        __syncthreads();
        if (tid < 16) {
            unsigned t = wsum[tid];
            #pragma unroll
            for (int off = 1; off < 16; off <<= 1) {
                unsigned u = __shfl_up(t, off);
                if (tid >= off) t += u;
            }
            wsum[tid] = t;
        }
        __syncthreads();
        unsigned woff = (w == 0) ? 0u : wsum[w - 1];
        if (i < n) cur[i] = carry + woff + s - v;
        unsigned tot = wsum[15];
        __syncthreads();
        carry += tot;
    }
}

__global__ void scatter_k(const int* __restrict__ ei, const float* __restrict__ ea,
                          unsigned* __restrict__ cur,
                          int* __restrict__ srcS, int* __restrict__ dstS,
                          float* __restrict__ eaS, int E) {
    int e = blockIdx.x * 256 + threadIdx.x;
    if (e >= E) return;
    int d = ei[E + e];
    unsigned pos = atomicAdd(&cur[d], 1u);
    srcS[pos] = ei[e];
    dstS[pos] = d;
    eaS[(size_t)pos * 3 + 0] = ea[(size_t)e * 3 + 0];
    eaS[(size_t)pos * 3 + 1] = ea[(size_t)e * 3 + 1];
    eaS[(size_t)pos * 3 + 2] = ea[(size_t)e * 3 + 2];
}

// ---------------- Edge kernel v10: one 32-edge tile/block, wave->2-column split ----------------
// B frags loaded once per block into regs; K-loops are pure LDS+MFMA; hierarchical merged atomics.
__global__ __launch_bounds__(256, 2)
void edge_mfma_v10(const unsigned short* __restrict__ xb,   // [N][128] bf16
                   const int* __restrict__ srcS,            // [E] (dst-sorted)
                   const int* __restrict__ dstS,            // [E]
                   const float* __restrict__ eaS,           // [E][3]
                   const unsigned short* __restrict__ W1f,  // [8][8][64][8] bf16
                   const unsigned short* __restrict__ W2f,  // [4][8][64][8] bf16
                   const float* __restrict__ W1tail,        // [3][128] fp32
                   const float* __restrict__ bm1,
                   const float* __restrict__ bm2,
                   float* __restrict__ agg,
                   int E)
{
    __shared__ alignas(16) char A[32 * 512];   // 16 KB: 32 edges x (src|dst) 256+256 B, swizzled
    __shared__ alignas(16) char H[32 * 256];   // 8 KB
    __shared__ int   sSrc[32], sDst[32];
    __shared__ float sEA[96];

    const int tid   = threadIdx.x;
    const int lane  = tid & 63;
    const int w     = tid >> 6;
    const int e0    = blockIdx.x * 32;
    const int arow  = lane & 15;
    const int kgrp  = (lane >> 4) << 4;
    const int rbase = (lane >> 4) * 4;

    // ---- B fragments for this wave's 2 columns: issue FIRST (latency overlaps staging) ----
    short8 B1[2][8], B2[2][4];
    #pragma unroll
    for (int i = 0; i < 2; ++i) {
        int nt = w * 2 + i;
        #pragma unroll
        for (int ks = 0; ks < 8; ++ks)
            B1[i][ks] = *(const short8*)(W1f + (size_t)((ks * 8 + nt) * 64 + lane) * 8);
        #pragma unroll
        for (int ks = 0; ks < 4; ++ks)
            B2[i][ks] = *(const short8*)(W2f + (size_t)((ks * 8 + nt) * 64 + lane) * 8);
    }
    float w1t[2][3], b1c[2], b2c[2];
    #pragma unroll
    for (int i = 0; i < 2; ++i) {
        int col = (w * 2 + i) * 16 + arow;
        w1t[i][0] = W1tail[col];
        w1t[i][1] = W1tail[128 + col];
        w1t[i][2] = W1tail[256 + col];
        b1c[i] = bm1[col];
        b2c[i] = bm2[col];
    }

    // ---- phase 1: indices + edge attrs ----
    if (tid < 32) {
        int e = e0 + tid; int ec = (e < E) ? e : (E - 1);
        sSrc[tid] = srcS[ec];
        sDst[tid] = dstS[ec];
    } else if (tid >= 64 && tid < 160) {
        int j = tid - 64;
        int eidx = e0 + j / 3, c = j - (j / 3) * 3;
        sEA[j] = (eidx < E) ? eaS[(size_t)eidx * 3 + c] : 0.f;
    }
    __syncthreads();

    // ---- phase 2: cooperative gather (coalesced 16-lane rows) ----
    #pragma unroll
    for (int k = 0; k < 4; ++k) {
        int g  = k * 256 + tid;
        int rr = g >> 4, c = g & 15;
        int el = rr & 31, half = rr >> 5;
        int node = half ? sDst[el] : sSrc[el];
        uint4 v = *(const uint4*)(xb + (size_t)node * 128 + c * 8);
        *(uint4*)(A + el * 512 + ((half * 256 + c * 16) ^ ((el & 15) << 4))) = v;
    }
    __syncthreads();

    // ---- phase 3: GEMM1 [32,256]@[256, 32 cols], pure LDS+MFMA ----
    f32x4 ac1[2][2];   // [nt-i][stream-m]
    #pragma unroll
    for (int i = 0; i < 2; ++i) { ac1[i][0] = (f32x4)0.f; ac1[i][1] = (f32x4)0.f; }
    #pragma unroll
    for (int ks = 0; ks < 8; ++ks) {
        int cb = (ks * 64 + kgrp) ^ (arow << 4);
        short8 a0 = *(const short8*)(A + arow * 512        + cb);
        short8 a1 = *(const short8*)(A + (16 + arow) * 512 + cb);
        #pragma unroll
        for (int i = 0; i < 2; ++i) {
            ac1[i][0] = __builtin_amdgcn_mfma_f32_16x16x32_bf16(a0, B1[i][ks], ac1[i][0], 0, 0, 0);
            ac1[i][1] = __builtin_amdgcn_mfma_f32_16x16x32_bf16(a1, B1[i][ks], ac1[i][1], 0, 0, 0);
        }
    }

    // ---- epilogue 1: + edge_attr (fp32 exact) + bias, relu, H -> LDS ----
    #pragma unroll
    for (int i = 0; i < 2; ++i) {
        int col = (w * 2 + i) * 16 + arow;
        #pragma unroll
        for (int m = 0; m < 2; ++m) {
            #pragma unroll
            for (int r = 0; r < 4; ++r) {
                int el = m * 16 + rbase + r;
                float h = ac1[i][m][r] + b1c[i];
                h = fmaf(sEA[el * 3 + 0], w1t[i][0], h);
                h = fmaf(sEA[el * 3 + 1], w1t[i][1], h);
                h = fmaf(sEA[el * 3 + 2], w1t[i][2], h);
                h = fmaxf(h, 0.f);
                *(unsigned short*)(H + el * 256 + ((col * 2) ^ ((el & 15) << 4))) = f2bf(h);
            }
        }
    }
    __syncthreads();

    // ---- phase 4: GEMM2 [32,128]@[128, 32 cols] ----
    f32x4 ac2[2][2];
    #pragma unroll
    for (int i = 0; i < 2; ++i) { ac2[i][0] = (f32x4)0.f; ac2[i][1] = (f32x4)0.f; }
    #pragma unroll
    for (int ks = 0; ks < 4; ++ks) {
        int cb = (ks * 64 + kgrp) ^ (arow << 4);
        short8 a0 = *(const short8*)(H + arow * 256        + cb);
        short8 a1 = *(const short8*)(H + (16 + arow) * 256 + cb);
        #pragma unroll
        for (int i = 0; i < 2; ++i) {
            ac2[i][0] = __builtin_amdgcn_mfma_f32_16x16x32_bf16(a0, B2[i][ks], ac2[i][0], 0, 0, 0);
            ac2[i][1] = __builtin_amdgcn_mfma_f32_16x16x32_bf16(a1, B2[i][ks], ac2[i][1], 0, 0, 0);
        }
    }

    // ---- epilogue 2: hierarchical merged atomics (sorted => endpoint checks suffice) ----
    const bool fullT = (e0 + 32 <= E);
    const int d0  = sDst[0],  d15v = sDst[15];
    const int d16 = sDst[16], d31v = sDst[31];

    if (fullT && d0 == d31v) {
        // all 32 edges -> one dst: 1 atomic per col
        #pragma unroll
        for (int i = 0; i < 2; ++i) {
            int col = (w * 2 + i) * 16 + arow;
            float s = ac2[i][0][0] + ac2[i][0][1] + ac2[i][0][2] + ac2[i][0][3]
                    + ac2[i][1][0] + ac2[i][1][1] + ac2[i][1][2] + ac2[i][1][3]
                    + 8.f * b2c[i];
            s += __shfl_xor(s, 16);
            s += __shfl_xor(s, 32);
            if ((lane >> 4) == 0)
                unsafeAtomicAdd(agg + (size_t)d0 * 128 + col, s);
        }
    } else if (fullT && d0 == d15v && d16 == d31v) {
        // each 16-edge stream uniform: 2 atomics per col
        #pragma unroll
        for (int i = 0; i < 2; ++i) {
            int col = (w * 2 + i) * 16 + arow;
            #pragma unroll
            for (int m = 0; m < 2; ++m) {
                float s = ac2[i][m][0] + ac2[i][m][1] + ac2[i][m][2] + ac2[i][m][3]
                        + 4.f * b2c[i];
                s += __shfl_xor(s, 16);
                s += __shfl_xor(s, 32);
                if ((lane >> 4) == 0)
                    unsafeAtomicAdd(agg + (size_t)(m ? d16 : d0) * 128 + col, s);
            }
        }
    } else {
        // fallback: per-lane run merge (r6-proven), with tail guards
        int dv[2][4];
        #pragma unroll
        for (int m = 0; m < 2; ++m)
            #pragma unroll
            for (int r = 0; r < 4; ++r) dv[m][r] = sDst[m * 16 + rbase + r];
        #pragma unroll
        for (int i = 0; i < 2; ++i) {
            int col = (w * 2 + i) * 16 + arow;
            float bb = b2c[i];
            #pragma unroll
            for (int m = 0; m < 2; ++m) {
                float carry = 0.f;
                int   cd    = -1;
                #pragma unroll
                for (int r = 0; r < 4; ++r) {
                    int eg = e0 + m * 16 + rbase + r;
                    if (eg < E) {
                        float v = ac2[i][m][r] + bb;
                        if (dv[m][r] == cd) {
                            carry += v;
                        } else {
                            if (cd >= 0) unsafeAtomicAdd(agg + (size_t)cd * 128 + col, carry);
                            cd = dv[m][r];
                            carry = v;
                        }
                    }
                }
                if (cd >= 0) unsafeAtomicAdd(agg + (size_t)cd * 128 + col, carry);
            }
        }
    }
}

// ---------------- Node kernel: bf16 MFMA with hi/lo split (near-fp32) ----------------
__global__ __launch_bounds__(256, 3)
void node_mfma(const float* __restrict__ x,
               const float* __restrict__ agg,
               const unsigned short* __restrict__ WgH, const unsigned short* __restrict__ WgL,
               const unsigned short* __restrict__ Wu1H, const unsigned short* __restrict__ Wu1L,
               const unsigned short* __restrict__ Wu2H, const unsigned short* __restrict__ Wu2L,
               const float* __restrict__ bg, const float* __restrict__ bu1,
               const float* __restrict__ bu2,
               const float* __restrict__ gamma, const float* __restrict__ beta,
               float* __restrict__ out, int N)
{
    __shared__ alignas(16) char Hs[4][8192];

    const int tid  = threadIdx.x;
    const int lane = tid & 63;
    const int wid  = tid >> 6;
    const int n0   = (blockIdx.x * 4 + wid) * 16;
    if (n0 >= N) return;

    const int arow = lane & 15;
    const int g4   = lane >> 4;

    int nr = n0 + arow; if (nr >= N) nr = N - 1;
    const float* px = x   + (size_t)nr * 128 + g4 * 8;
    const float* pa = agg + (size_t)nr * 128 + g4 * 8;

    short8 ah[8], al[8];
    #pragma unroll
    for (int ks = 0; ks < 8; ++ks) {
        const float* p = (ks < 4) ? (px + ks * 32) : (pa + (ks - 4) * 32);
        float4 v0 = *(const float4*)p;
        float4 v1 = *(const float4*)(p + 4);
        float v[8] = { v0.x, v0.y, v0.z, v0.w, v1.x, v1.y, v1.z, v1.w };
        #pragma unroll
        for (int j = 0; j < 8; ++j) {
            unsigned short h = f2bf(v[j]);
            ah[ks][j] = (short)h;
            al[ks][j] = (short)f2bf(v[j] - bf2f(h));
        }
    }

    f32x4 ga[8];
    #pragma unroll
    for (int i = 0; i < 8; ++i) ga[i] = (f32x4)0.f;
    #pragma unroll
    for (int ks = 0; ks < 8; ++ks) {
        #pragma unroll
        for (int nt = 0; nt < 8; ++nt) {
            size_t o = (size_t)((ks * 8 + nt) * 64 + lane) * 8;
            short8 bh = *(const short8*)(WgH + o);
            short8 bl = *(const short8*)(WgL + o);
            ga[nt] = __builtin_amdgcn_mfma_f32_16x16x32_bf16(ah[ks], bh, ga[nt], 0, 0, 0);
            ga[nt] = __builtin_amdgcn_mfma_f32_16x16x32_bf16(al[ks], bh, ga[nt], 0, 0, 0);
            ga[nt] = __builtin_amdgcn_mfma_f32_16x16x32_bf16(ah[ks], bl, ga[nt], 0, 0, 0);
        }
    }

    f32x4 ua[8];
    #pragma unroll
    for (int i = 0; i < 8; ++i) ua[i] = (f32x4)0.f;
    #pragma unroll
    for (int ks = 0; ks < 8; ++ks) {
        #pragma unroll
        for (int nt = 0; nt < 8; ++nt) {
            size_t o = (size_t)((ks * 8 + nt) * 64 + lane) * 8;
            short8 bh = *(const short8*)(Wu1H + o);
            short8 bl = *(const short8*)(Wu1L + o);
            ua[nt] = __builtin_amdgcn_mfma_f32_16x16x32_bf16(ah[ks], bh, ua[nt], 0, 0, 0);
            ua[nt] = __builtin_amdgcn_mfma_f32_16x16x32_bf16(al[ks], bh, ua[nt], 0, 0, 0);
            ua[nt] = __builtin_amdgcn_mfma_f32_16x16x32_bf16(ah[ks], bl, ua[nt], 0, 0, 0);
        }
    }

    #pragma unroll
    for (int nt = 0; nt < 8; ++nt) {
        int col = nt * 16 + arow;
        float b1 = bu1[col];
        #pragma unroll
        for (int r = 0; r < 4; ++r) {
            int row = g4 * 4 + r;
            float u = fmaxf(ua[nt][r] + b1, 0.f);
            unsigned short h = f2bf(u);
            unsigned short l = f2bf(u - bf2f(h));
            unsigned int pk = (unsigned int)h | ((unsigned int)l << 16);
            *(unsigned int*)(&Hs[wid][row * 512 + ((col * 4) ^ ((row & 15) << 4))]) = pk;
        }
    }

    #pragma unroll
    for (int nt = 0; nt < 8; ++nt) {
        int col = nt * 16 + arow;
        float b = bg[col];
        #pragma unroll
        for (int r = 0; r < 4; ++r)
            ga[nt][r] = 1.f / (1.f + expf(-(ga[nt][r] + b)));
    }
    __syncthreads();

    f32x4 u2[8];
    #pragma unroll
    for (int i = 0; i < 8; ++i) u2[i] = (f32x4)0.f;
    #pragma unroll
    for (int ks = 0; ks < 4; ++ks) {
        int b0 = ks * 128 + g4 * 32;
        unsigned int q0[4], q1[4];
        *(uint4*)q0 = *(const uint4*)(&Hs[wid][arow * 512 + ( b0       ^ (arow << 4))]);
        *(uint4*)q1 = *(const uint4*)(&Hs[wid][arow * 512 + ((b0 + 16) ^ (arow << 4))]);
        short8 a2h, a2l;
        #pragma unroll
        for (int j = 0; j < 4; ++j) {
            a2h[j]     = (short)(q0[j] & 0xffff);
            a2l[j]     = (short)(q0[j] >> 16);
            a2h[4 + j] = (short)(q1[j] & 0xffff);
            a2l[4 + j] = (short)(q1[j] >> 16);
        }
        #pragma unroll
        for (int nt = 0; nt < 8; ++nt) {
            size_t o = (size_t)((ks * 8 + nt) * 64 + lane) * 8;
            short8 bh = *(const short8*)(Wu2H + o);
            short8 bl = *(const short8*)(Wu2L + o);
            u2[nt] = __builtin_amdgcn_mfma_f32_16x16x32_bf16(a2h, bh, u2[nt], 0, 0, 0);
            u2[nt] = __builtin_amdgcn_mfma_f32_16x16x32_bf16(a2l, bh, u2[nt], 0, 0, 0);
            u2[nt] = __builtin_amdgcn_mfma_f32_16x16x32_bf16(a2h, bl, u2[nt], 0, 0, 0);
        }
    }

    float s[4]  = {0.f, 0.f, 0.f, 0.f};
    float ss[4] = {0.f, 0.f, 0.f, 0.f};
    #pragma unroll
    for (int nt = 0; nt < 8; ++nt) {
        int col = nt * 16 + arow;
        float b2 = bu2[col];
        #pragma unroll
        for (int r = 0; r < 4; ++r) {
            int node = n0 + g4 * 4 + r;
            float xv = x[(size_t)node * 128 + col];
            float g  = ga[nt][r];
            float o  = g * (u2[nt][r] + b2) + (1.f - g) * xv;
            u2[nt][r] = o;
            s[r]  += o;
            ss[r] += o * o;
        }
    }
    #pragma unroll
    for (int off = 8; off >= 1; off >>= 1) {
        #pragma unroll
        for (int r = 0; r < 4; ++r) {
            s[r]  += __shfl_xor(s[r],  off);
            ss[r] += __shfl_xor(ss[r], off);
        }
    }
    float mu[4], rstd[4];
    #pragma unroll
    for (int r = 0; r < 4; ++r) {
        mu[r] = s[r] * (1.f / 128.f);
        float var = ss[r] * (1.f / 128.f) - mu[r] * mu[r];
        rstd[r] = rsqrtf(var + 1e-5f);
    }
    #pragma unroll
    for (int nt = 0; nt < 8; ++nt) {
        int col = nt * 16 + arow;
        float gm = gamma[col], bt = beta[col];
        #pragma unroll
        for (int r = 0; r < 4; ++r) {
            int node = n0 + g4 * 4 + r;
            if (node < N)
                out[(size_t)node * 128 + col] = (u2[nt][r] - mu[r]) * rstd[r] * gm + bt;
        }
    }
}

extern "C" void kernel_launch(void* const* d_in, const int* in_sizes, int n_in,
                              void* d_out, int out_size, void* d_ws, size_t ws_size,
                              hipStream_t stream)
{
    const float* x    = (const float*)d_in[0];
    const int*   ei   = (const int*)  d_in[1];
    const float* ea   = (const float*)d_in[2];
    const float* Wm1  = (const float*)d_in[3];
    const float* bm1  = (const float*)d_in[4];
    const float* Wm2  = (const float*)d_in[5];
    const float* bm2  = (const float*)d_in[6];
    const float* Wg   = (const float*)d_in[7];
    const float* bg   = (const float*)d_in[8];
    const float* Wu1  = (const float*)d_in[9];
    const float* bu1  = (const float*)d_in[10];
    const float* Wu2  = (const float*)d_in[11];
    const float* bu2  = (const float*)d_in[12];
    const float* gmma = (const float*)d_in[13];
    const float* beta = (const float*)d_in[14];
    float* out = (float*)d_out;

    const int N = in_sizes[0] / HID;
    const int E = in_sizes[1] / 2;

    // workspace carve-up (r6 layout)
    float*          agg  = (float*)d_ws;                             // N*128 f32
    unsigned short* xb   = (unsigned short*)(agg + (size_t)N * HID); // N*128 bf16
    unsigned short* W1f  = xb + (size_t)N * HID;                     // 32768
    unsigned short* W2f  = W1f + 32768;                              // 16384
    unsigned short* WgH  = W2f + 16384;
    unsigned short* WgL  = WgH + 32768;
    unsigned short* Wu1H = WgL + 32768;
    unsigned short* Wu1L = Wu1H + 32768;
    unsigned short* Wu2H = Wu1L + 32768;
    unsigned short* Wu2L = Wu2H + 16384;
    unsigned* cnt  = (unsigned*)(Wu2L + 16384);   // N counters
    unsigned* cur  = cnt + N;                     // N cursors
    int*      srcS = (int*)(cur + N);             // E
    int*      dstS = srcS + E;                    // E
    float*    eaS  = (float*)(dstS + E);          // E*3
    size_t need = (size_t)((char*)(eaS + (size_t)E * 3) - (char*)d_ws);
    const bool do_sort = (ws_size >= need);

    hipMemsetAsync(agg, 0, (size_t)N * HID * sizeof(float), stream);

    int n4 = N * HID / 4;
    prep_x<<<dim3((n4 + 255) / 256), dim3(256), 0, stream>>>((const float4*)x, xb, n4);
    prep_w<<<dim3(16), dim3(256), 0, stream>>>(Wm1, W1f, 8);
    prep_w<<<dim3(8),  dim3(256), 0, stream>>>(Wm2, W2f, 4);
    prep_w_split<<<dim3(16), dim3(256), 0, stream>>>(Wg,  WgH,  WgL,  8);
    prep_w_split<<<dim3(16), dim3(256), 0, stream>>>(Wu1, Wu1H, Wu1L, 8);
    prep_w_split<<<dim3(8),  dim3(256), 0, stream>>>(Wu2, Wu2H, Wu2L, 4);

    const int*   srcA = ei;
    const int*   dstA = ei + E;
    const float* eaA  = ea;
    if (do_sort) {
        hipMemsetAsync(cnt, 0, (size_t)N * sizeof(unsigned), stream);
        hist_k<<<dim3((E + 255) / 256), dim3(256), 0, stream>>>(ei, cnt, E);
        scan_k<<<dim3(1), dim3(1024), 0, stream>>>(cnt, cur, N);
        scatter_k<<<dim3((E + 255) / 256), dim3(256), 0, stream>>>(ei, ea, cur, srcS, dstS, eaS, E);
        srcA = srcS; dstA = dstS; eaA = eaS;
    }

    edge_mfma_v10<<<dim3((E + 31) / 32), dim3(256), 0, stream>>>(
        xb, srcA, dstA, eaA, W1f, W2f, Wm1 + 256 * HID, bm1, bm2, agg, E);

    int ntilesN = (N + 15) / 16;
    node_mfma<<<dim3((ntilesN + 3) / 4), dim3(256), 0, stream>>>(
        x, agg, WgH, WgL, Wu1H, Wu1L, Wu2H, Wu2L,
        bg, bu1, bu2, gmma, beta, out, N);
}